// Round 9
// baseline (486.831 us; speedup 1.0000x reference)
//
#include <hip/hip_runtime.h>

typedef float f4v __attribute__((ext_vector_type(4)));
typedef float f2v __attribute__((ext_vector_type(2)));
typedef short s8v __attribute__((ext_vector_type(8)));

#define TT 128
#define II 28
#define HH 200
#define BB 16          // batch rows per block (= per wave)
#define SH 232         // Hs row stride in bf16: 464 B, 16B-aligned
#define CH 8           // timesteps per x chunk
#define XW (CH * BB * II)   // 3584 f32 per chunk buffer

// round-half-up f32->bf16 pair, packed: 2 adds + 1 v_perm
__device__ __forceinline__ unsigned pk_hu(float a, float b) {
    unsigned ua = __builtin_bit_cast(unsigned, a) + 0x8000u;
    unsigned ub = __builtin_bit_cast(unsigned, b) + 0x8000u;
    return __builtin_amdgcn_perm(ub, ua, 0x07060302);
}
__device__ __forceinline__ short f2bf(float f) {
    return (short)((__builtin_bit_cast(unsigned, f) + 0x8000u) >> 16);
}

__global__ __launch_bounds__(64, 1)
void rnn_pw(const float* __restrict__ x,
            const float* __restrict__ W_ih,
            const float* __restrict__ W_hh,
            const float* __restrict__ b_ih,
            const float* __restrict__ b_hh,
            const float* __restrict__ W_fc,
            const float* __restrict__ b_fc,
            float* __restrict__ out)
{
    // One wave per block: NO barriers anywhere. Same-wave DS ops are in-order.
    // LDS: Hs 16*232*2 = 7424 B + Xl 2*3592*4 = 28736 B => ~35.3 KB
    __shared__ __align__(16) short Hs[BB][SH];     // bf16 h: cols 0..199; 200..207 garbage*0;
                                                   // col 208 = 1.0 (bias column); 209..223 = 0
    __shared__ __align__(16) float Xl[2][XW + 8];  // raw f32 x chunks [t][r][c]

    const int lane = threadIdx.x & 63;
    const int q    = lane >> 4;   // quad 0..3
    const int lr   = lane & 15;   // A: j-in-tile ; B/C: batch row
    const int b0   = blockIdx.x * BB;

    // init h0 = 0 and pads; then the bias-one column
    for (int i = lane; i < BB * SH / 2; i += 64) ((int*)Hs)[i] = 0;
    if (lane < BB) Hs[lane][208] = (short)0x3F80;   // bf16 1.0

    // ---- full W~ resident in unified VGPR/AGPR: A-frag(u,kc) = W~[16u+lr][32kc+8q+i]
    // W~[j][k] = W_hh[j][k] (k<200) | bias[j] (k==208) | W_ih[j][k-224] (224<=k<252) | 0
    s8v Af[13][8];
    #pragma unroll
    for (int u = 0; u < 13; ++u) {
        const int j = 16 * u + lr;
        #pragma unroll
        for (int kc = 0; kc < 8; ++kc) {
            union { short s[8]; s8v v; } tv;
            #pragma unroll
            for (int i = 0; i < 8; ++i) {
                const int k = 32 * kc + 8 * q + i;
                float w = 0.0f;
                if (j < HH) {
                    if (k < HH)                     w = W_hh[j * HH + k];
                    else if (k == 208)              w = b_ih[j] + b_hh[j];
                    else if (k >= 224 && k < 252)   w = W_ih[j * II + (k - 224)];
                }
                tv.s[i] = f2bf(w);
            }
            Af[u][kc] = tv.v;
        }
    }

    // ---- x DMA: this wave stages its own 16 rows, 8 steps per chunk (14 x 16B x 64 lanes) ----
    long xoff[14];
    #pragma unroll
    for (int e = 0; e < 14; ++e) {
        const int m  = (e << 6) + lane;
        const int tl = m / 112;
        const int rm = m - tl * 112;
        const int r  = rm / 7;
        const int c4 = rm - r * 7;
        xoff[e] = ((long)(b0 + r) * TT + tl) * II + c4 * 4;
    }
    auto load_chunk = [&](int cc) {
        float* dbase = &Xl[cc & 1][0];
        #pragma unroll
        for (int e = 0; e < 14; ++e) {
            const float* src = x + xoff[e] + (long)cc * (CH * II);
            __builtin_amdgcn_global_load_lds(
                (const __attribute__((address_space(1))) void*)src,
                (__attribute__((address_space(3))) void*)(dbase + e * 256),
                16, 0, 0);
        }
    };

    load_chunk(0);

    const f4v zero = {0.f, 0.f, 0.f, 0.f};

    for (int c = 0; c < TT / CH; ++c) {
        __builtin_amdgcn_s_waitcnt(0);        // drain this chunk's DMA (issued 8 steps ago)
        if (c + 1 < TT / CH) load_chunk(c + 1);

        for (int s = 0; s < CH; ++s) {
            // x frag: LDS f32 -> bf16 (q=3 tail cols >= 28 meet zero weights)
            const float* xr = &Xl[c & 1][s * (BB * II) + lr * II + 8 * q];
            const f2v x0 = *(const f2v*)(xr + 0);
            const f2v x1 = *(const f2v*)(xr + 2);
            const f2v x2 = *(const f2v*)(xr + 4);
            const f2v x3 = *(const f2v*)(xr + 6);
            union { unsigned u4[4]; s8v v; } xf;
            xf.u4[0] = pk_hu(x0.x, x0.y);
            xf.u4[1] = pk_hu(x1.x, x1.y);
            xf.u4[2] = pk_hu(x2.x, x2.y);
            xf.u4[3] = pk_hu(x3.x, x3.y);

            // 13 independent MFMA chains; kc-outer -> dep distance 13 (fully pipelined).
            // kc7 (x, register-fed) first: h-frag reads land underneath it.
            s8v cur = *(const s8v*)&Hs[lr][8 * q];   // kc0
            f4v acc[13];
            #pragma unroll
            for (int u = 0; u < 13; ++u)
                acc[u] = __builtin_amdgcn_mfma_f32_16x16x32_bf16(Af[u][7], xf.v, zero, 0, 0, 0);
            #pragma unroll
            for (int kc = 0; kc < 7; ++kc) {
                s8v nxt;
                if (kc < 6) nxt = *(const s8v*)&Hs[lr][32 * (kc + 1) + 8 * q];
                #pragma unroll
                for (int u = 0; u < 13; ++u)
                    acc[u] = __builtin_amdgcn_mfma_f32_16x16x32_bf16(Af[u][kc], cur, acc[u], 0, 0, 0);
                if (kc < 6) cur = nxt;
            }

            // relu -> bf16 -> Hs (same wave reads it next step; in-order DS, no sync)
            #pragma unroll
            for (int u = 0; u < 13; ++u) {
                const float r0 = fmaxf(acc[u].x, 0.f), r1 = fmaxf(acc[u].y, 0.f);
                const float r2 = fmaxf(acc[u].z, 0.f), r3 = fmaxf(acc[u].w, 0.f);
                int2 hv;
                hv.x = (int)pk_hu(r0, r1);
                hv.y = (int)pk_hu(r2, r3);
                *(int2*)&Hs[lr][16 * u + 4 * q] = hv;   // tile 12 upper rows -> cols 200..207 (*0 next step)
            }
        }
    }

    // ---- FC epilogue: h_T bf16 in Hs ----
    for (int i = lane; i < BB * 10; i += 64) {
        const int o = i >> 4, r = i & 15;
        float sacc = b_fc[o];
        for (int k = 0; k < HH; ++k) {
            const float hk = __builtin_bit_cast(float,
                (unsigned)((unsigned short)Hs[r][k]) << 16);
            sacc = fmaf(hk, W_fc[o * HH + k], sacc);
        }
        __builtin_nontemporal_store(sacc, &out[(long)(b0 + r) * 10 + o]);
    }
}

extern "C" void kernel_launch(void* const* d_in, const int* in_sizes, int n_in,
                              void* d_out, int out_size, void* d_ws, size_t ws_size,
                              hipStream_t stream) {
    const float* x    = (const float*)d_in[0];
    const float* W_ih = (const float*)d_in[1];
    const float* W_hh = (const float*)d_in[2];
    const float* b_ih = (const float*)d_in[3];
    const float* b_hh = (const float*)d_in[4];
    const float* W_fc = (const float*)d_in[5];
    const float* b_fc = (const float*)d_in[6];
    float* out = (float*)d_out;

    rnn_pw<<<dim3(8192 / BB), dim3(64), 0, stream>>>(
        x, W_ih, W_hh, b_ih, b_hh, W_fc, b_fc, out);
}